// Round 15
// baseline (185.147 us; speedup 1.0000x reference)
//
#include <hip/hip_runtime.h>
#include <hip/hip_bf16.h>
#include <stdint.h>

#define B_    16
#define C_    320
#define S_    4096
#define G_    32
#define LC    77
#define CTX   768
#define HEADS 8
#define HD    40

typedef __bf16 bf16x8_t __attribute__((ext_vector_type(8)));
typedef float  f32x4_t  __attribute__((ext_vector_type(4)));

__device__ __forceinline__ unsigned short f2bf(float f) {
    union { float f; unsigned int u; } v; v.f = f;
    unsigned int r = v.u + 0x7fffu + ((v.u >> 16) & 1u);
    return (unsigned short)(r >> 16);
}
__device__ __forceinline__ float bf2f(unsigned short h) {
    union { unsigned int u; float f; } v; v.u = ((unsigned int)h) << 16;
    return v.f;
}

// async global->LDS, 16B per lane (dest = wave-uniform base + lane*16)
__device__ __forceinline__ void gload16(const void* g, void* l) {
    __builtin_amdgcn_global_load_lds(
        (const __attribute__((address_space(1))) unsigned int*)g,
        (__attribute__((address_space(3))) unsigned int*)l, 16, 0, 0);
}

// ---------------------------------------------------------------- GN stats
__global__ __launch_bounds__(256) void gn_stats(const float* __restrict__ x,
                                                float2* __restrict__ mr) {
    int bg = blockIdx.x;
    const float4* p = (const float4*)(x + (size_t)bg * 40960);
    float s = 0.f, s2 = 0.f;
    for (int i = threadIdx.x; i < 10240; i += 256) {
        float4 v = p[i];
        s  += v.x + v.y + v.z + v.w;
        s2 += v.x * v.x + v.y * v.y + v.z * v.z + v.w * v.w;
    }
    for (int o = 32; o; o >>= 1) {
        s  += __shfl_down(s, o);
        s2 += __shfl_down(s2, o);
    }
    __shared__ float2 red[4];
    int lane = threadIdx.x & 63, wid = threadIdx.x >> 6;
    if (lane == 0) red[wid] = make_float2(s, s2);
    __syncthreads();
    if (threadIdx.x == 0) {
        float a = 0.f, c = 0.f;
        for (int i = 0; i < 4; i++) { a += red[i].x; c += red[i].y; }
        float mean = a / 40960.f;
        float var  = c / 40960.f - mean * mean;
        mr[bg] = make_float2(mean, rsqrtf(var + 1e-5f));
    }
}

// ---------------------------------------------------------------- weight cast
__global__ __launch_bounds__(256) void castw(const float* __restrict__ s,
                                             unsigned short* __restrict__ d) {
    int i = blockIdx.x * 256 + threadIdx.x;
    float4 v = ((const float4*)s)[i];
    ushort4 o;
    o.x = f2bf(v.x); o.y = f2bf(v.y); o.z = f2bf(v.z); o.w = f2bf(v.w);
    ((ushort4*)d)[i] = o;
}

// ---------------------------------------------------------------- normalize + transpose
__global__ __launch_bounds__(256) void norm_tr(const float* __restrict__ x,
                                               const float2* __restrict__ mr,
                                               const float* __restrict__ gns,
                                               const float* __restrict__ gnb,
                                               unsigned short* __restrict__ tok) {
    int s0 = blockIdx.x * 32, c0 = blockIdx.y * 32, b = blockIdx.z;
    __shared__ unsigned short t[32][33];
    int tx = threadIdx.x & 31, ty = threadIdx.x >> 5;
    #pragma unroll
    for (int i = 0; i < 4; i++) {
        int cl = i * 8 + ty;
        int c = c0 + cl;
        float2 m = mr[b * 32 + c / 10];
        float v = x[((size_t)(b * 320 + c)) * 4096 + s0 + tx];
        v = (v - m.x) * m.y * gns[c] + gnb[c];
        t[cl][tx] = f2bf(v);
    }
    __syncthreads();
    #pragma unroll
    for (int i = 0; i < 4; i++) {
        int sl = i * 8 + ty;
        tok[((size_t)b * 4096 + s0 + sl) * 320 + c0 + tx] = t[tx][sl];
    }
}

// ---------------------------------------------------------------- U kernel
__global__ __launch_bounds__(256) void ukern(const float* __restrict__ Wk,
                                             const float* __restrict__ Wq,
                                             unsigned short* __restrict__ Ut) {
    int c = blockIdx.x, h = blockIdx.y;
    int t = threadIdx.x;
    float a0 = 0.f, a1 = 0.f, a2 = 0.f;
    for (int d = 0; d < HD; d++) {
        float wq = Wq[(size_t)(h * HD + d) * 320 + c];
        const float* wkr = Wk + (size_t)(h * HD + d) * CTX;
        a0 += wq * wkr[t];
        a1 += wq * wkr[t + 256];
        a2 += wq * wkr[t + 512];
    }
    unsigned short* o = Ut + ((size_t)h * 320 + c) * CTX;
    o[t]       = f2bf(a0);
    o[t + 256] = f2bf(a1);
    o[t + 512] = f2bf(a2);
}

// ---------------------------------------------------------------- fused K/V/M projection GEMM
// cols 0..319: V = ctx @ Wv^T.  cols 320..2879: M_h = ctx @ Ut_h, written
// PRE-SWIZZLED into [80][320] tiles (idx16 ^= kv&7) for attn9's linear
// global_load_lds staging + conflict-free ds_read_b128.
__global__ __launch_bounds__(256) void kvM_gemm(const float* __restrict__ ctx,
                                                const float* __restrict__ Wv,
                                                const unsigned short* __restrict__ Ut,
                                                unsigned short* __restrict__ vout,
                                                unsigned short* __restrict__ Mout) {
    __shared__ unsigned short la[64][32], lb[64][32];
    int bm = blockIdx.x, bn = blockIdx.y;
    int tid = threadIdx.x, lane = tid & 63, wid = tid >> 6;
    int wm = wid >> 1, wn = wid & 1;
    int lr = tid >> 2, lc = (tid & 3) * 8;
    int fr = lane & 15, kk = (lane >> 4) * 8;

    int arow = bm * 64 + lr; if (arow > 1231) arow = 1231;
    const float* ap = ctx + (size_t)arow * CTX;
    bool isV = (bn < 5);
    const float* wp = isV ? (Wv + (size_t)(bn * 64 + lr) * CTX) : nullptr;
    const unsigned short* up = isV ? nullptr
        : (Ut + ((size_t)((bn - 5) / 5) * 320 + (size_t)((bn - 5) % 5) * 64 + lr) * CTX);

    f32x4_t acc[2][2] = {};
    for (int k0 = 0; k0 < CTX; k0 += 32) {
        float4 a4 = *(const float4*)&ap[k0 + lc];
        float4 a5 = *(const float4*)&ap[k0 + lc + 4];
        ushort4 pa0 = { f2bf(a4.x), f2bf(a4.y), f2bf(a4.z), f2bf(a4.w) };
        ushort4 pa1 = { f2bf(a5.x), f2bf(a5.y), f2bf(a5.z), f2bf(a5.w) };
        *(ushort4*)&la[lr][lc]     = pa0;
        *(ushort4*)&la[lr][lc + 4] = pa1;
        if (isV) {
            float4 w4 = *(const float4*)&wp[k0 + lc];
            float4 w5 = *(const float4*)&wp[k0 + lc + 4];
            ushort4 pw0 = { f2bf(w4.x), f2bf(w4.y), f2bf(w4.z), f2bf(w4.w) };
            ushort4 pw1 = { f2bf(w5.x), f2bf(w5.y), f2bf(w5.z), f2bf(w5.w) };
            *(ushort4*)&lb[lr][lc]     = pw0;
            *(ushort4*)&lb[lr][lc + 4] = pw1;
        } else {
            *(uint4*)&lb[lr][lc] = *(const uint4*)&up[k0 + lc];
        }
        __syncthreads();
        bf16x8_t a0 = *(const bf16x8_t*)&la[wm * 32 + fr][kk];
        bf16x8_t a1 = *(const bf16x8_t*)&la[wm * 32 + 16 + fr][kk];
        bf16x8_t b0 = *(const bf16x8_t*)&lb[wn * 32 + fr][kk];
        bf16x8_t b1 = *(const bf16x8_t*)&lb[wn * 32 + 16 + fr][kk];
        acc[0][0] = __builtin_amdgcn_mfma_f32_16x16x32_bf16(a0, b0, acc[0][0], 0, 0, 0);
        acc[0][1] = __builtin_amdgcn_mfma_f32_16x16x32_bf16(a0, b1, acc[0][1], 0, 0, 0);
        acc[1][0] = __builtin_amdgcn_mfma_f32_16x16x32_bf16(a1, b0, acc[1][0], 0, 0, 0);
        acc[1][1] = __builtin_amdgcn_mfma_f32_16x16x32_bf16(a1, b1, acc[1][1], 0, 0, 0);
        __syncthreads();
    }
    int rg = (lane >> 4) * 4;
    #pragma unroll
    for (int mf = 0; mf < 2; mf++)
        #pragma unroll
        for (int nf = 0; nf < 2; nf++)
            #pragma unroll
            for (int r = 0; r < 4; r++) {
                int row = bm * 64 + wm * 32 + mf * 16 + rg + r;
                if (row < 1232) {
                    int coloff = wn * 32 + nf * 16 + fr;
                    unsigned short val = f2bf(acc[mf][nf][r]);
                    if (isV) {
                        vout[(size_t)row * 320 + bn * 64 + coloff] = val;
                    } else {
                        int bb = row / 77, kv = row - bb * 77;
                        int hh = (bn - 5) / 5;
                        int c = ((bn - 5) % 5) * 64 + coloff;
                        size_t tile = ((size_t)bb * 8 + hh) * 25600;
                        int idx16 = kv * 40 + (c >> 3);
                        int swz = idx16 ^ (kv & 7);
                        Mout[tile + (size_t)swz * 8 + (c & 7)] = val;
                    }
                }
            }
}

// ---------------------------------------------------------------- fused attention v9b
// = R14's attn9 (two-piece M staging, 36.6KB LDS -> 4 blocks/CU) with the NaN
// fix: zero Msr shorts [15360,18304) once in the prologue. That tail (Vt rows
// >=20 incl. all cols 77..103) is never written by piece-A staging (covers
// shorts [0,15360)), piece-B staging ([0,10240)), or Vt writes (cols 0..76).
// Uninitialized LDS there can be NaN bf16 patterns; PV multiplies those cols
// by P=0 and 0*NaN=NaN poisoned stored outputs in R14.
__global__ __launch_bounds__(256, 2) void attn9(const unsigned short* __restrict__ tok,
                                                const unsigned short* __restrict__ M,
                                                const unsigned short* __restrict__ v,
                                                unsigned short* __restrict__ att) {
    __shared__ unsigned short Msr[18304];  // 36,608 B
    unsigned short (*Ps)[104] = (unsigned short (*)[104])Msr;            // [0, 13312)
    unsigned short (*Vt)[104] = (unsigned short (*)[104])(Msr + 13312);  // [13312, 18304)

    int tid = threadIdx.x;
    int qt = blockIdx.x, b = blockIdx.y, h0 = blockIdx.z * 4;
    int q0 = qt * 128;
    int lane = tid & 63, wv = tid >> 6;
    int fr = lane & 15, fg = lane >> 4;
    const float scale = 0.15811388300841898f;  // 1/sqrt(40)

    // prologue: stage M piece A (rows 0..47) for h0
    {
        const unsigned short* Mt = M + ((size_t)b * 8 + h0) * 25600;
        #pragma unroll
        for (int i = 0; i < 8; i++) {
            int u = i * 256 + tid;
            if (u < 1920) gload16(Mt + (size_t)u * 8, &Msr[u * 8]);
        }
    }
    // NaN fix: zero the never-restaged LDS tail [15360, 18304) (368 uint4,
    // disjoint from the piece-A stage -> no ordering hazard)
    {
        uint4 z = {0, 0, 0, 0};
        uint4* zp = (uint4*)&Msr[15360];
        if (tid < 256) {
            zp[tid] = z;
            if (tid + 256 < 368 + 256 && tid < 112) zp[256 + tid] = z;
        }
    }
    // V loads h0 (kv = idx%77: row-uniform LDS writes later)
    uint4 vreg0, vreg1;
    {
        int kv = tid % 77, sg = tid / 77;
        vreg0 = *(const uint4*)&v[((size_t)(b * LC + kv)) * 320 + h0 * HD + sg * 8];
        int idx = tid + 256;
        if (idx < 385) {
            kv = idx % 77; sg = idx / 77;
            vreg1 = *(const uint4*)&v[((size_t)(b * LC + kv)) * 320 + h0 * HD + sg * 8];
        }
    }
    // tok fragments -> registers (whole kernel)
    bf16x8_t atok[2][10];
    const size_t tokbase = ((size_t)b * S_ + q0) * 320;
    #pragma unroll
    for (int mf = 0; mf < 2; mf++)
        #pragma unroll
        for (int k = 0; k < 10; k++)
            atok[mf][k] = *(const bf16x8_t*)&tok[tokbase + (size_t)(wv * 32 + mf * 16 + fr) * 320 + k * 32 + fg * 8];

    __syncthreads();  // drain piece-A stage + zero writes for h0

    for (int i = 0; i < 4; i++) {   // NO unroll: keeps live ranges per-iteration
        int h = h0 + i;
        f32x4_t sc[2][5] = {};

        // ---- scores phase A: nf = 0,1,2 (kv rows 0..47)
        __builtin_amdgcn_s_setprio(1);
        #pragma unroll
        for (int k = 0; k < 10; k++) {
            bf16x8_t bb[3];
            #pragma unroll
            for (int nf = 0; nf < 3; nf++) {
                int idx16 = (nf * 16 + fr) * 40 + k * 4 + fg;
                bb[nf] = *(const bf16x8_t*)&Msr[(size_t)(idx16 ^ (fr & 7)) * 8];
            }
            #pragma unroll
            for (int mf = 0; mf < 2; mf++)
                #pragma unroll
                for (int nf = 0; nf < 3; nf++)
                    sc[mf][nf] = __builtin_amdgcn_mfma_f32_16x16x32_bf16(atok[mf][k], bb[nf], sc[mf][nf], 0, 0, 0);
        }
        __builtin_amdgcn_s_setprio(0);
        __syncthreads();  // bar1: all waves done reading piece A

        // ---- stage piece B (rows 48..79, chunks 1920..3199) -> LDS offset 0
        {
            const unsigned short* Mh = M + ((size_t)b * 8 + h) * 25600;
            #pragma unroll
            for (int j = 0; j < 5; j++) {
                int u = j * 256 + tid;  // 0..1279
                gload16(Mh + (size_t)(1920 + u) * 8, &Msr[u * 8]);
            }
        }
        // ---- write Vt from vregs (cols 0..76: disjoint from B stage)
        {
            unsigned short e[8];
            int kv = tid % 77, sg = tid / 77;
            *(uint4*)e = vreg0;
            #pragma unroll
            for (int j = 0; j < 8; j++) Vt[sg * 8 + j][kv] = e[j];
            int idx = tid + 256;
            if (idx < 385) {
                kv = idx % 77; sg = idx / 77;
                *(uint4*)e = vreg1;
                #pragma unroll
                for (int j = 0; j < 8; j++) Vt[sg * 8 + j][kv] = e[j];
            }
        }
        __syncthreads();  // bar2: piece B ready (vmcnt drained), Vt visible

        // ---- scores phase B: nf = 3,4 (kv rows 48..79, LDS offset -1920 chunks)
        __builtin_amdgcn_s_setprio(1);
        #pragma unroll
        for (int k = 0; k < 10; k++) {
            bf16x8_t bb[2];
            #pragma unroll
            for (int nf2 = 0; nf2 < 2; nf2++) {
                int idx16 = ((3 + nf2) * 16 + fr) * 40 + k * 4 + fg;
                int lds16 = (idx16 ^ (fr & 7)) - 1920;
                bb[nf2] = *(const bf16x8_t*)&Msr[(size_t)lds16 * 8];
            }
            #pragma unroll
            for (int mf = 0; mf < 2; mf++)
                #pragma unroll
                for (int nf2 = 0; nf2 < 2; nf2++)
                    sc[mf][3 + nf2] = __builtin_amdgcn_mfma_f32_16x16x32_bf16(atok[mf][k], bb[nf2], sc[mf][3 + nf2], 0, 0, 0);
        }
        __builtin_amdgcn_s_setprio(0);
        __syncthreads();  // bar3: all waves done reading piece B

        // ---- zero own-wave Ps pad cols [80,96) (B region dead now)
        {
            uint4 z = {0, 0, 0, 0};
            int zr = wv * 32 + (lane >> 1);
            *(uint4*)((char*)&Ps[zr][80] + (lane & 1) * 16) = z;
        }

        // ---- softmax, m=0 (exact; range safe for GN'd scores)
        float sm[2][4];
        #pragma unroll
        for (int mf = 0; mf < 2; mf++)
            #pragma unroll
            for (int r = 0; r < 4; r++) {
                float s = 0.f;
                #pragma unroll
                for (int nf = 0; nf < 5; nf++) {
                    float p = (nf < 4 || fr < 13) ? __expf(sc[mf][nf][r] * scale) : 0.f;
                    sc[mf][nf][r] = p;
                    s += p;
                }
                sm[mf][r] = s;
            }
        #pragma unroll
        for (int off = 1; off < 16; off <<= 1)
            #pragma unroll
            for (int mf = 0; mf < 2; mf++)
                #pragma unroll
                for (int r = 0; r < 4; r++)
                    sm[mf][r] += __shfl_xor(sm[mf][r], off);

        // ---- P -> LDS (wave-private rows)
        #pragma unroll
        for (int mf = 0; mf < 2; mf++)
            #pragma unroll
            for (int nf = 0; nf < 5; nf++)
                #pragma unroll
                for (int r = 0; r < 4; r++)
                    Ps[wv * 32 + mf * 16 + fg * 4 + r][nf * 16 + fr] = f2bf(sc[mf][nf][r]);

        __syncthreads();  // bar4: Ps visible to all waves

        // ---- PV
        f32x4_t ov[2][3] = {};
        __builtin_amdgcn_s_setprio(1);
        #pragma unroll
        for (int ks = 0; ks < 3; ks++) {
            bf16x8_t vb[3];
            #pragma unroll
            for (int nf = 0; nf < 3; nf++)
                vb[nf] = *(const bf16x8_t*)&Vt[nf * 16 + fr][ks * 32 + fg * 8];
            #pragma unroll
            for (int mf = 0; mf < 2; mf++) {
                bf16x8_t pa = *(const bf16x8_t*)&Ps[wv * 32 + mf * 16 + fr][ks * 32 + fg * 8];
                #pragma unroll
                for (int nf = 0; nf < 3; nf++)
                    ov[mf][nf] = __builtin_amdgcn_mfma_f32_16x16x32_bf16(pa, vb[nf], ov[mf][nf], 0, 0, 0);
            }
        }
        __builtin_amdgcn_s_setprio(0);
        __syncthreads();  // bar5: PV done reading Ps/Vt

        // ---- stage piece A for h+1 (overwrites dead Ps + Vt[0,2048)) + V loads h+1
        if (i < 3) {
            const unsigned short* Mn = M + ((size_t)b * 8 + h + 1) * 25600;
            #pragma unroll
            for (int j = 0; j < 8; j++) {
                int u = j * 256 + tid;
                if (u < 1920) gload16(Mn + (size_t)u * 8, &Msr[u * 8]);
            }
            int kv = tid % 77, sg = tid / 77;
            vreg0 = *(const uint4*)&v[((size_t)(b * LC + kv)) * 320 + (h + 1) * HD + sg * 8];
            int idx = tid + 256;
            if (idx < 385) {
                kv = idx % 77; sg = idx / 77;
                vreg1 = *(const uint4*)&v[((size_t)(b * LC + kv)) * 320 + (h + 1) * HD + sg * 8];
            }
        }

        // ---- normalize + store att[b][h][s][d] (contiguous per head)
        #pragma unroll
        for (int mf = 0; mf < 2; mf++) {
            float inv[4];
            #pragma unroll
            for (int r = 0; r < 4; r++) inv[r] = 1.f / sm[mf][r];
            #pragma unroll
            for (int nf = 0; nf < 3; nf++) {
                int d = nf * 16 + fr;
                if (d < HD) {
                    #pragma unroll
                    for (int r = 0; r < 4; r++) {
                        int qrow = q0 + wv * 32 + mf * 16 + fg * 4 + r;
                        att[((size_t)(b * 8 + h) * S_ + qrow) * 40 + d] = f2bf(ov[mf][nf][r] * inv[r]);
                    }
                }
            }
        }
        if (i < 3) __syncthreads();  // bar6: drain piece-A stage before next scores
    }
}

// ---------------------------------------------------------------- output projection v2 (proven ~44us)
// out[b][n][s] = sum_e att[b][e/40][s][e%40] * Wo[n][e] + bo[n] + resid[b][n][s]
__global__ __launch_bounds__(256) void gemm_oproj2(const unsigned short* __restrict__ att,
                                                   const unsigned short* __restrict__ wo,
                                                   const float* __restrict__ bo,
                                                   const float* __restrict__ resid,
                                                   float* __restrict__ out) {
    __shared__ unsigned short lw[320 * 40];  // Wo K-slice, 25.6 KB
    __shared__ unsigned short la[64 * 40];   // att K-slice, 5.1 KB
    int tid = threadIdx.x, lane = tid & 63, wv = tid >> 6;
    int fr = lane & 15, fg = lane >> 4;
    int bm = blockIdx.x, b = blockIdx.y;
    int s0 = bm * 64;

    f32x4_t acc[5][4] = {};  // [n-frag][s-frag]

    for (int k0 = 0; k0 < 320; k0 += 32) {
        #pragma unroll
        for (int i = 0; i < 7; i++) {
            int u = i * 256 + tid;
            if (u < 1600) {
                int row = u / 5, ch = u % 5;
                int c = ch < 4 ? ch : 0;  // pad chunk: never read
                gload16(wo + (size_t)row * 320 + k0 + c * 8, &lw[(size_t)u * 8]);
            }
        }
        {
            int u = tid;
            int row = u / 5, ch = u % 5;
            int c = ch < 4 ? ch : 0;
            int e0 = k0 + c * 8;
            gload16(att + ((size_t)(b * 8 + e0 / 40) * S_ + s0 + row) * 40 + e0 % 40,
                    &la[(size_t)u * 8]);
            u = tid + 256;
            if (u < 320) {
                row = u / 5; ch = u % 5; c = ch < 4 ? ch : 0;
                e0 = k0 + c * 8;
                gload16(att + ((size_t)(b * 8 + e0 / 40) * S_ + s0 + row) * 40 + e0 % 40,
                        &la[(size_t)u * 8]);
            }
        }
        __syncthreads();  // drains vmcnt -> LDS ready
        bf16x8_t bfrag[4];
        #pragma unroll
        for (int sf = 0; sf < 4; sf++)
            bfrag[sf] = *(const bf16x8_t*)&la[(sf * 16 + fr) * 40 + fg * 8];
        #pragma unroll
        for (int nf = 0; nf < 5; nf++) {
            bf16x8_t afrag = *(const bf16x8_t*)&lw[(wv * 80 + nf * 16 + fr) * 40 + fg * 8];
            #pragma unroll
            for (int sf = 0; sf < 4; sf++)
                acc[nf][sf] = __builtin_amdgcn_mfma_f32_16x16x32_bf16(afrag, bfrag[sf], acc[nf][sf], 0, 0, 0);
        }
        __syncthreads();
    }

    // epilogue: direct coalesced stores, bias + residual
    int nbase = wv * 80;
    #pragma unroll
    for (int nf = 0; nf < 5; nf++) {
        #pragma unroll
        for (int r = 0; r < 4; r++) {
            int n = nbase + nf * 16 + fg * 4 + r;
            float bov = bo[n];
            size_t rowb = ((size_t)(b * 320 + n)) * 4096 + s0;
            #pragma unroll
            for (int sf = 0; sf < 4; sf++) {
                int s = sf * 16 + fr;
                out[rowb + s] = acc[nf][sf][r] + bov + resid[rowb + s];
            }
        }
    }
}

// ---------------------------------------------------------------- launch
extern "C" void kernel_launch(void* const* d_in, const int* in_sizes, int n_in,
                              void* d_out, int out_size, void* d_ws, size_t ws_size,
                              hipStream_t stream) {
    const float* x    = (const float*)d_in[0];
    const float* ctx  = (const float*)d_in[1];
    const float* Wq   = (const float*)d_in[2];
    const float* Wk   = (const float*)d_in[3];
    const float* Wv   = (const float*)d_in[4];
    const float* Wo   = (const float*)d_in[5];
    const float* bo   = (const float*)d_in[6];
    const float* gns  = (const float*)d_in[7];
    const float* gnb  = (const float*)d_in[8];
    float* out = (float*)d_out;

    char* ws = (char*)d_ws;
    float2*         mr    = (float2*)(ws + 0);                 //      4,096
    unsigned short* wo_bf = (unsigned short*)(ws + 4096);      //    204,800 -> 208,896
    unsigned short* v_bf  = (unsigned short*)(ws + 208896);    //    788,480 -> 997,376
    unsigned short* Mbuf  = (unsigned short*)(ws + 997376);    //  6,553,600 -> 7,550,976
    unsigned short* tok   = (unsigned short*)(ws + 7550976);   // 41,943,040 -> 49,494,016
    unsigned short* att   = (unsigned short*)(ws + 49494016);  // 41,943,040 -> 91,437,056
    unsigned short* Ut    = att;                               //  3,932,160 (alias, disjoint lifetime)

    gn_stats<<<512, 256, 0, stream>>>(x, mr);
    castw<<<100, 256, 0, stream>>>(Wo, wo_bf);
    ukern<<<dim3(320, 8), 256, 0, stream>>>(Wk, Wq, Ut);
    kvM_gemm<<<dim3(20, 45), 256, 0, stream>>>(ctx, Wv, Ut, v_bf, Mbuf);
    norm_tr<<<dim3(128, 10, 16), 256, 0, stream>>>(x, mr, gns, gnb, tok);
    attn9<<<dim3(32, 16, 2), 256, 0, stream>>>(tok, Mbuf, v_bf, att);
    gemm_oproj2<<<dim3(64, 16), 256, 0, stream>>>(att, wo_bf, bo, x, out);
}

// Round 16
// 182.501 us; speedup vs baseline: 1.0145x; 1.0145x over previous
//
#include <hip/hip_runtime.h>
#include <hip/hip_bf16.h>
#include <stdint.h>

#define B_    16
#define C_    320
#define S_    4096
#define G_    32
#define LC    77
#define CTX   768
#define HEADS 8
#define HD    40

typedef __bf16 bf16x8_t __attribute__((ext_vector_type(8)));
typedef float  f32x4_t  __attribute__((ext_vector_type(4)));

__device__ __forceinline__ unsigned short f2bf(float f) {
    union { float f; unsigned int u; } v; v.f = f;
    unsigned int r = v.u + 0x7fffu + ((v.u >> 16) & 1u);
    return (unsigned short)(r >> 16);
}
__device__ __forceinline__ float bf2f(unsigned short h) {
    union { unsigned int u; float f; } v; v.u = ((unsigned int)h) << 16;
    return v.f;
}

// async global->LDS, 16B per lane (dest = wave-uniform base + lane*16)
__device__ __forceinline__ void gload16(const void* g, void* l) {
    __builtin_amdgcn_global_load_lds(
        (const __attribute__((address_space(1))) unsigned int*)g,
        (__attribute__((address_space(3))) unsigned int*)l, 16, 0, 0);
}

// ---------------------------------------------------------------- GN stats
__global__ __launch_bounds__(256) void gn_stats(const float* __restrict__ x,
                                                float2* __restrict__ mr) {
    int bg = blockIdx.x;
    const float4* p = (const float4*)(x + (size_t)bg * 40960);
    float s = 0.f, s2 = 0.f;
    for (int i = threadIdx.x; i < 10240; i += 256) {
        float4 v = p[i];
        s  += v.x + v.y + v.z + v.w;
        s2 += v.x * v.x + v.y * v.y + v.z * v.z + v.w * v.w;
    }
    for (int o = 32; o; o >>= 1) {
        s  += __shfl_down(s, o);
        s2 += __shfl_down(s2, o);
    }
    __shared__ float2 red[4];
    int lane = threadIdx.x & 63, wid = threadIdx.x >> 6;
    if (lane == 0) red[wid] = make_float2(s, s2);
    __syncthreads();
    if (threadIdx.x == 0) {
        float a = 0.f, c = 0.f;
        for (int i = 0; i < 4; i++) { a += red[i].x; c += red[i].y; }
        float mean = a / 40960.f;
        float var  = c / 40960.f - mean * mean;
        mr[bg] = make_float2(mean, rsqrtf(var + 1e-5f));
    }
}

// ---------------------------------------------------------------- weight cast
__global__ __launch_bounds__(256) void castw(const float* __restrict__ s,
                                             unsigned short* __restrict__ d) {
    int i = blockIdx.x * 256 + threadIdx.x;
    float4 v = ((const float4*)s)[i];
    ushort4 o;
    o.x = f2bf(v.x); o.y = f2bf(v.y); o.z = f2bf(v.z); o.w = f2bf(v.w);
    ((ushort4*)d)[i] = o;
}

// ---------------------------------------------------------------- normalize + transpose
__global__ __launch_bounds__(256) void norm_tr(const float* __restrict__ x,
                                               const float2* __restrict__ mr,
                                               const float* __restrict__ gns,
                                               const float* __restrict__ gnb,
                                               unsigned short* __restrict__ tok) {
    int s0 = blockIdx.x * 32, c0 = blockIdx.y * 32, b = blockIdx.z;
    __shared__ unsigned short t[32][33];
    int tx = threadIdx.x & 31, ty = threadIdx.x >> 5;
    #pragma unroll
    for (int i = 0; i < 4; i++) {
        int cl = i * 8 + ty;
        int c = c0 + cl;
        float2 m = mr[b * 32 + c / 10];
        float v = x[((size_t)(b * 320 + c)) * 4096 + s0 + tx];
        v = (v - m.x) * m.y * gns[c] + gnb[c];
        t[cl][tx] = f2bf(v);
    }
    __syncthreads();
    #pragma unroll
    for (int i = 0; i < 4; i++) {
        int sl = i * 8 + ty;
        tok[((size_t)b * 4096 + s0 + sl) * 320 + c0 + tx] = t[tx][sl];
    }
}

// ---------------------------------------------------------------- U kernel
__global__ __launch_bounds__(256) void ukern(const float* __restrict__ Wk,
                                             const float* __restrict__ Wq,
                                             unsigned short* __restrict__ Ut) {
    int c = blockIdx.x, h = blockIdx.y;
    int t = threadIdx.x;
    float a0 = 0.f, a1 = 0.f, a2 = 0.f;
    for (int d = 0; d < HD; d++) {
        float wq = Wq[(size_t)(h * HD + d) * 320 + c];
        const float* wkr = Wk + (size_t)(h * HD + d) * CTX;
        a0 += wq * wkr[t];
        a1 += wq * wkr[t + 256];
        a2 += wq * wkr[t + 512];
    }
    unsigned short* o = Ut + ((size_t)h * 320 + c) * CTX;
    o[t]       = f2bf(a0);
    o[t + 256] = f2bf(a1);
    o[t + 512] = f2bf(a2);
}

// ---------------------------------------------------------------- fused K/V/M projection GEMM
// cols 0..319: V = ctx @ Wv^T.  cols 320..2879: M_h = ctx @ Ut_h, written
// PRE-SWIZZLED into [80][320] tiles (idx16 ^= kv&7) for attn8's linear
// global_load_lds staging + conflict-free ds_read_b128.
__global__ __launch_bounds__(256) void kvM_gemm(const float* __restrict__ ctx,
                                                const float* __restrict__ Wv,
                                                const unsigned short* __restrict__ Ut,
                                                unsigned short* __restrict__ vout,
                                                unsigned short* __restrict__ Mout) {
    __shared__ unsigned short la[64][32], lb[64][32];
    int bm = blockIdx.x, bn = blockIdx.y;
    int tid = threadIdx.x, lane = tid & 63, wid = tid >> 6;
    int wm = wid >> 1, wn = wid & 1;
    int lr = tid >> 2, lc = (tid & 3) * 8;
    int fr = lane & 15, kk = (lane >> 4) * 8;

    int arow = bm * 64 + lr; if (arow > 1231) arow = 1231;
    const float* ap = ctx + (size_t)arow * CTX;
    bool isV = (bn < 5);
    const float* wp = isV ? (Wv + (size_t)(bn * 64 + lr) * CTX) : nullptr;
    const unsigned short* up = isV ? nullptr
        : (Ut + ((size_t)((bn - 5) / 5) * 320 + (size_t)((bn - 5) % 5) * 64 + lr) * CTX);

    f32x4_t acc[2][2] = {};
    for (int k0 = 0; k0 < CTX; k0 += 32) {
        float4 a4 = *(const float4*)&ap[k0 + lc];
        float4 a5 = *(const float4*)&ap[k0 + lc + 4];
        ushort4 pa0 = { f2bf(a4.x), f2bf(a4.y), f2bf(a4.z), f2bf(a4.w) };
        ushort4 pa1 = { f2bf(a5.x), f2bf(a5.y), f2bf(a5.z), f2bf(a5.w) };
        *(ushort4*)&la[lr][lc]     = pa0;
        *(ushort4*)&la[lr][lc + 4] = pa1;
        if (isV) {
            float4 w4 = *(const float4*)&wp[k0 + lc];
            float4 w5 = *(const float4*)&wp[k0 + lc + 4];
            ushort4 pw0 = { f2bf(w4.x), f2bf(w4.y), f2bf(w4.z), f2bf(w4.w) };
            ushort4 pw1 = { f2bf(w5.x), f2bf(w5.y), f2bf(w5.z), f2bf(w5.w) };
            *(ushort4*)&lb[lr][lc]     = pw0;
            *(ushort4*)&lb[lr][lc + 4] = pw1;
        } else {
            *(uint4*)&lb[lr][lc] = *(const uint4*)&up[k0 + lc];
        }
        __syncthreads();
        bf16x8_t a0 = *(const bf16x8_t*)&la[wm * 32 + fr][kk];
        bf16x8_t a1 = *(const bf16x8_t*)&la[wm * 32 + 16 + fr][kk];
        bf16x8_t b0 = *(const bf16x8_t*)&lb[wn * 32 + fr][kk];
        bf16x8_t b1 = *(const bf16x8_t*)&lb[wn * 32 + 16 + fr][kk];
        acc[0][0] = __builtin_amdgcn_mfma_f32_16x16x32_bf16(a0, b0, acc[0][0], 0, 0, 0);
        acc[0][1] = __builtin_amdgcn_mfma_f32_16x16x32_bf16(a0, b1, acc[0][1], 0, 0, 0);
        acc[1][0] = __builtin_amdgcn_mfma_f32_16x16x32_bf16(a1, b0, acc[1][0], 0, 0, 0);
        acc[1][1] = __builtin_amdgcn_mfma_f32_16x16x32_bf16(a1, b1, acc[1][1], 0, 0, 0);
        __syncthreads();
    }
    int rg = (lane >> 4) * 4;
    #pragma unroll
    for (int mf = 0; mf < 2; mf++)
        #pragma unroll
        for (int nf = 0; nf < 2; nf++)
            #pragma unroll
            for (int r = 0; r < 4; r++) {
                int row = bm * 64 + wm * 32 + mf * 16 + rg + r;
                if (row < 1232) {
                    int coloff = wn * 32 + nf * 16 + fr;
                    unsigned short val = f2bf(acc[mf][nf][r]);
                    if (isV) {
                        vout[(size_t)row * 320 + bn * 64 + coloff] = val;
                    } else {
                        int bb = row / 77, kv = row - bb * 77;
                        int hh = (bn - 5) / 5;
                        int c = ((bn - 5) % 5) * 64 + coloff;
                        size_t tile = ((size_t)bb * 8 + hh) * 25600;
                        int idx16 = kv * 40 + (c >> 3);
                        int swz = idx16 ^ (kv & 7);
                        Mout[tile + (size_t)swz * 8 + (c & 7)] = val;
                    }
                }
            }
}

// ---------------------------------------------------------------- fused attention v8 (R13, proven 60.4us)
__global__ __launch_bounds__(256, 2) void attn8(const unsigned short* __restrict__ tok,
                                                const unsigned short* __restrict__ M,
                                                const unsigned short* __restrict__ v,
                                                unsigned short* __restrict__ att) {
    __shared__ unsigned short Msr[25600];  // 51,200 B
    unsigned short (*Ps)[104] = (unsigned short (*)[104])Msr;            // 13312 shorts
    unsigned short (*Vt)[104] = (unsigned short (*)[104])(Msr + 13312);  // 4992 shorts

    int tid = threadIdx.x;
    int qt = blockIdx.x, b = blockIdx.y, h0 = blockIdx.z * 4;
    int q0 = qt * 128;
    int lane = tid & 63, wv = tid >> 6;
    int fr = lane & 15, fg = lane >> 4;
    const float scale = 0.15811388300841898f;  // 1/sqrt(40)

    // stage M tile h0 (linear: source pre-swizzled)
    {
        const unsigned short* Mt = M + ((size_t)b * 8 + h0) * 25600;
        #pragma unroll
        for (int i = 0; i < 13; i++) {
            int u = i * 256 + tid;
            if (u < 3200) gload16(Mt + (size_t)u * 8, &Msr[u * 8]);
        }
    }
    // V loads h0 (kv = idx%77, sg = idx/77 -> row-uniform LDS writes later)
    uint4 vreg0, vreg1;
    {
        int kv = tid % 77, sg = tid / 77;
        vreg0 = *(const uint4*)&v[((size_t)(b * LC + kv)) * 320 + h0 * HD + sg * 8];
        int idx = tid + 256;
        if (idx < 385) {
            kv = idx % 77; sg = idx / 77;
            vreg1 = *(const uint4*)&v[((size_t)(b * LC + kv)) * 320 + h0 * HD + sg * 8];
        }
    }
    // tok fragments -> registers (whole kernel)
    bf16x8_t atok[2][10];
    const size_t tokbase = ((size_t)b * S_ + q0) * 320;
    #pragma unroll
    for (int mf = 0; mf < 2; mf++)
        #pragma unroll
        for (int k = 0; k < 10; k++)
            atok[mf][k] = *(const bf16x8_t*)&tok[tokbase + (size_t)(wv * 32 + mf * 16 + fr) * 320 + k * 32 + fg * 8];

    __syncthreads();  // (A0) drains M stage

    for (int i = 0; i < 4; i++) {   // NO unroll: keeps live ranges per-iteration
        int h = h0 + i;

        // ---- scores: S = tok @ M_h^T (regs x swizzled LDS), K = 320
        f32x4_t sc[2][5] = {};
        __builtin_amdgcn_s_setprio(1);
        #pragma unroll
        for (int k = 0; k < 10; k++) {
            bf16x8_t bb[5];
            #pragma unroll
            for (int nf = 0; nf < 5; nf++) {
                int idx16 = (nf * 16 + fr) * 40 + k * 4 + fg;
                bb[nf] = *(const bf16x8_t*)&Msr[(size_t)(idx16 ^ (fr & 7)) * 8];
            }
            #pragma unroll
            for (int mf = 0; mf < 2; mf++)
                #pragma unroll
                for (int nf = 0; nf < 5; nf++)
                    sc[mf][nf] = __builtin_amdgcn_mfma_f32_16x16x32_bf16(atok[mf][k], bb[nf], sc[mf][nf], 0, 0, 0);
        }
        __builtin_amdgcn_s_setprio(0);
        __syncthreads();  // (d) all waves done reading M

        // ---- write Vt (aliased into Msr) from vregs — row-uniform, conflict-free
        {
            unsigned short e[8];
            int kv = tid % 77, sg = tid / 77;
            *(uint4*)e = vreg0;
            #pragma unroll
            for (int j = 0; j < 8; j++) Vt[sg * 8 + j][kv] = e[j];
            int idx = tid + 256;
            if (idx < 385) {
                kv = idx % 77; sg = idx / 77;
                *(uint4*)e = vreg1;
                #pragma unroll
                for (int j = 0; j < 8; j++) Vt[sg * 8 + j][kv] = e[j];
            }
        }

        // ---- zero own-wave Ps pad cols [80,96)
        {
            uint4 z = {0, 0, 0, 0};
            int zr = wv * 32 + (lane >> 1);
            *(uint4*)((char*)&Ps[zr][80] + (lane & 1) * 16) = z;
        }

        // ---- softmax, m=0 (exact; range safe for GN'd scores)
        float sm[2][4];
        #pragma unroll
        for (int mf = 0; mf < 2; mf++)
            #pragma unroll
            for (int r = 0; r < 4; r++) {
                float s = 0.f;
                #pragma unroll
                for (int nf = 0; nf < 5; nf++) {
                    float p = (nf < 4 || fr < 13) ? __expf(sc[mf][nf][r] * scale) : 0.f;
                    sc[mf][nf][r] = p;
                    s += p;
                }
                sm[mf][r] = s;
            }
        #pragma unroll
        for (int off = 1; off < 16; off <<= 1)
            #pragma unroll
            for (int mf = 0; mf < 2; mf++)
                #pragma unroll
                for (int r = 0; r < 4; r++)
                    sm[mf][r] += __shfl_xor(sm[mf][r], off);

        // ---- P -> LDS (wave-private rows)
        #pragma unroll
        for (int mf = 0; mf < 2; mf++)
            #pragma unroll
            for (int nf = 0; nf < 5; nf++)
                #pragma unroll
                for (int r = 0; r < 4; r++)
                    Ps[wv * 32 + mf * 16 + fg * 4 + r][nf * 16 + fr] = f2bf(sc[mf][nf][r]);

        __syncthreads();  // (d2) Vt + Ps visible to all waves

        // ---- PV
        f32x4_t ov[2][3] = {};
        __builtin_amdgcn_s_setprio(1);
        #pragma unroll
        for (int ks = 0; ks < 3; ks++) {
            bf16x8_t vb[3];
            #pragma unroll
            for (int nf = 0; nf < 3; nf++)
                vb[nf] = *(const bf16x8_t*)&Vt[nf * 16 + fr][ks * 32 + fg * 8];
            #pragma unroll
            for (int mf = 0; mf < 2; mf++) {
                bf16x8_t pa = *(const bf16x8_t*)&Ps[wv * 32 + mf * 16 + fr][ks * 32 + fg * 8];
                #pragma unroll
                for (int nf = 0; nf < 3; nf++)
                    ov[mf][nf] = __builtin_amdgcn_mfma_f32_16x16x32_bf16(pa, vb[nf], ov[mf][nf], 0, 0, 0);
            }
        }
        __builtin_amdgcn_s_setprio(0);
        __syncthreads();  // (f) all waves done reading Ps/Vt

        // ---- stage M_{h+1} (async overwrite of Msr) + issue V loads h+1
        if (i < 3) {
            const unsigned short* Mn = M + ((size_t)b * 8 + h + 1) * 25600;
            #pragma unroll
            for (int j = 0; j < 13; j++) {
                int u = j * 256 + tid;
                if (u < 3200) gload16(Mn + (size_t)u * 8, &Msr[u * 8]);
            }
            int kv = tid % 77, sg = tid / 77;
            vreg0 = *(const uint4*)&v[((size_t)(b * LC + kv)) * 320 + (h + 1) * HD + sg * 8];
            int idx = tid + 256;
            if (idx < 385) {
                kv = idx % 77; sg = idx / 77;
                vreg1 = *(const uint4*)&v[((size_t)(b * LC + kv)) * 320 + (h + 1) * HD + sg * 8];
            }
        }

        // ---- normalize + store att[b][h][s][d] (contiguous per head)
        #pragma unroll
        for (int mf = 0; mf < 2; mf++) {
            float inv[4];
            #pragma unroll
            for (int r = 0; r < 4; r++) inv[r] = 1.f / sm[mf][r];
            #pragma unroll
            for (int nf = 0; nf < 3; nf++) {
                int d = nf * 16 + fr;
                if (d < HD) {
                    #pragma unroll
                    for (int r = 0; r < 4; r++) {
                        int qrow = q0 + wv * 32 + mf * 16 + fg * 4 + r;
                        att[((size_t)(b * 8 + h) * S_ + qrow) * 40 + d] = f2bf(ov[mf][nf][r] * inv[r]);
                    }
                }
            }
        }
        if (i < 3) __syncthreads();  // (i) drains stage vmcnt before next scores
    }
}

// ---------------------------------------------------------------- output projection v5
// = oproj2 with DOUBLE-BUFFERED LDS: stage k+1 while MFMAs consume k, ONE
// barrier per k-step (its vmcnt-drain readies the next buffer and fences
// reuse). Named buffers via 2x-unrolled k-loop (compile-time LDS bases).
__global__ __launch_bounds__(256) void gemm_oproj5(const unsigned short* __restrict__ att,
                                                   const unsigned short* __restrict__ wo,
                                                   const float* __restrict__ bo,
                                                   const float* __restrict__ resid,
                                                   float* __restrict__ out) {
    __shared__ unsigned short lw0[1600 * 8], la0[320 * 8];  // 25.6 + 5.1 KB
    __shared__ unsigned short lw1[1600 * 8], la1[320 * 8];  // x2 = 61,440 B
    int tid = threadIdx.x, lane = tid & 63, wv = tid >> 6;
    int fr = lane & 15, fg = lane >> 4;
    int bm = blockIdx.x, b = blockIdx.y;
    int s0 = bm * 64;

    f32x4_t acc[5][4] = {};  // [n-frag][s-frag]

    // stage helper (macro-style lambdas; all LDS bases compile-time)
    auto stage = [&](unsigned short* lw, unsigned short* la, int k0) {
        #pragma unroll
        for (int i = 0; i < 7; i++) {
            int u = i * 256 + tid;
            if (u < 1600) {
                int row = u / 5, ch = u % 5;
                int c = ch < 4 ? ch : 0;  // pad chunk: never read
                gload16(wo + (size_t)row * 320 + k0 + c * 8, &lw[(size_t)u * 8]);
            }
        }
        {
            int u = tid;
            int row = u / 5, ch = u % 5;
            int c = ch < 4 ? ch : 0;
            int e0 = k0 + c * 8;
            gload16(att + ((size_t)(b * 8 + e0 / 40) * S_ + s0 + row) * 40 + e0 % 40,
                    &la[(size_t)u * 8]);
            u = tid + 256;
            if (u < 320) {
                row = u / 5; ch = u % 5; c = ch < 4 ? ch : 0;
                e0 = k0 + c * 8;
                gload16(att + ((size_t)(b * 8 + e0 / 40) * S_ + s0 + row) * 40 + e0 % 40,
                        &la[(size_t)u * 8]);
            }
        }
    };
    auto compute = [&](const unsigned short* lw, const unsigned short* la) {
        bf16x8_t bfrag[4];
        #pragma unroll
        for (int sf = 0; sf < 4; sf++)
            bfrag[sf] = *(const bf16x8_t*)&la[(sf * 16 + fr) * 40 + fg * 8];
        #pragma unroll
        for (int nf = 0; nf < 5; nf++) {
            bf16x8_t afrag = *(const bf16x8_t*)&lw[(wv * 80 + nf * 16 + fr) * 40 + fg * 8];
            #pragma unroll
            for (int sf = 0; sf < 4; sf++)
                acc[nf][sf] = __builtin_amdgcn_mfma_f32_16x16x32_bf16(afrag, bfrag[sf], acc[nf][sf], 0, 0, 0);
        }
    };

    stage(lw0, la0, 0);
    __syncthreads();  // buf0 ready
    #pragma unroll
    for (int kq = 0; kq < 5; kq++) {
        int k0 = kq * 64;
        stage(lw1, la1, k0 + 32);    // issue next while computing buf0
        compute(lw0, la0);
        __syncthreads();             // buf1 ready; buf0 reads done
        if (k0 + 64 < 320) stage(lw0, la0, k0 + 64);
        compute(lw1, la1);
        __syncthreads();             // buf0 ready; buf1 reads done
    }

    // epilogue: direct coalesced stores, bias + residual
    int nbase = wv * 80;
    #pragma unroll
    for (int nf = 0; nf < 5; nf++) {
        #pragma unroll
        for (int r = 0; r < 4; r++) {
            int n = nbase + nf * 16 + fg * 4 + r;
            float bov = bo[n];
            size_t rowb = ((size_t)(b * 320 + n)) * 4096 + s0;
            #pragma unroll
            for (int sf = 0; sf < 4; sf++) {
                int s = sf * 16 + fr;
                out[rowb + s] = acc[nf][sf][r] + bov + resid[rowb + s];
            }
        }
    }
}

// ---------------------------------------------------------------- launch
extern "C" void kernel_launch(void* const* d_in, const int* in_sizes, int n_in,
                              void* d_out, int out_size, void* d_ws, size_t ws_size,
                              hipStream_t stream) {
    const float* x    = (const float*)d_in[0];
    const float* ctx  = (const float*)d_in[1];
    const float* Wq   = (const float*)d_in[2];
    const float* Wk   = (const float*)d_in[3];
    const float* Wv   = (const float*)d_in[4];
    const float* Wo   = (const float*)d_in[5];
    const float* bo   = (const float*)d_in[6];
    const float* gns  = (const float*)d_in[7];
    const float* gnb  = (const float*)d_in[8];
    float* out = (float*)d_out;

    char* ws = (char*)d_ws;
    float2*         mr    = (float2*)(ws + 0);                 //      4,096
    unsigned short* wo_bf = (unsigned short*)(ws + 4096);      //    204,800 -> 208,896
    unsigned short* v_bf  = (unsigned short*)(ws + 208896);    //    788,480 -> 997,376
    unsigned short* Mbuf  = (unsigned short*)(ws + 997376);    //  6,553,600 -> 7,550,976
    unsigned short* tok   = (unsigned short*)(ws + 7550976);   // 41,943,040 -> 49,494,016
    unsigned short* att   = (unsigned short*)(ws + 49494016);  // 41,943,040 -> 91,437,056
    unsigned short* Ut    = att;                               //  3,932,160 (alias, disjoint lifetime)

    gn_stats<<<512, 256, 0, stream>>>(x, mr);
    castw<<<100, 256, 0, stream>>>(Wo, wo_bf);
    ukern<<<dim3(320, 8), 256, 0, stream>>>(Wk, Wq, Ut);
    kvM_gemm<<<dim3(20, 45), 256, 0, stream>>>(ctx, Wv, Ut, v_bf, Mbuf);
    norm_tr<<<dim3(128, 10, 16), 256, 0, stream>>>(x, mr, gns, gnb, tok);
    attn8<<<dim3(32, 16, 2), 256, 0, stream>>>(tok, Mbuf, v_bf, att);
    gemm_oproj5<<<dim3(64, 16), 256, 0, stream>>>(att, wo_bf, bo, x, out);
}